// Round 5
// baseline (146.582 us; speedup 1.0000x reference)
//
#include <hip/hip_runtime.h>
#include <hip/hip_bf16.h>

typedef __attribute__((ext_vector_type(8))) short short8;
typedef __attribute__((ext_vector_type(4))) float f32x4;

#define LL 2048
#define DD 128
#define NH 32                      // B*H heads
#define SCALE 0.08838834764831845f // 1/sqrt(128)

__device__ __forceinline__ unsigned short f2bf(float f) {
  unsigned int u = __float_as_uint(f);
  u = u + 0x7FFFu + ((u >> 16) & 1u);  // RNE; inputs finite
  return (unsigned short)(u >> 16);
}
__device__ __forceinline__ unsigned int pk2(float a, float b) {
  return (unsigned int)f2bf(a) | ((unsigned int)f2bf(b) << 16);
}
__device__ __forceinline__ float fc(const float4& v, int c) {
  return ((const float*)&v)[c];
}

// ---------------------------------------------------------------------------
// Kernel 1: per-chunk partial W_p[d2][d1] = sum_{m in chunk} V[m][d2]*K[m][d1]
// grid = 32 heads * 16 chunks (128 m-rows each), block = 512 (8 waves).
// Whole chunk staged in LDS at once (70KB): 16 global_load_dwordx4 issued up
// front per thread, transpose in completion order, ONE barrier, then
// 4 k-tiles x 8 MFMA per wave. HBM latency exposed once per block, not 4x.
// ---------------------------------------------------------------------------
template <bool PARTIAL>
__global__ __launch_bounds__(512, 4) void ktv_kernel(const float* __restrict__ Kg,
                                                     const float* __restrict__ Vg,
                                                     float* __restrict__ P) {
  const int bh = blockIdx.x >> 4;
  const int chunk = blockIdx.x & 15;
  const int t = threadIdx.x;

  __shared__ unsigned short Kt[128][136];  // [d1][m], 272B rows
  __shared__ unsigned short Vt[128][136];  // [d2][m]

  const int wave = t >> 6;
  const int lane = t & 63;
  const int lr = lane & 15;
  const int kg = lane >> 4;

  const int dq = t >> 4;        // 0..31 : d-quad (4 floats at dq*4)
  const int mr = (t & 15) << 1; // 0..30 : m-row pair base
  const size_t hb = (size_t)bh * LL * DD;
  const float* kbase = Kg + hb + (size_t)(chunk * 128 + mr) * DD + dq * 4;
  const float* vbase = Vg + hb + (size_t)(chunk * 128 + mr) * DD + dq * 4;

  // issue ALL loads (16 dwordx4 in flight per thread)
  float4 kv[4][2], vv[4][2];
#pragma unroll
  for (int tile = 0; tile < 4; ++tile)
#pragma unroll
    for (int r = 0; r < 2; ++r) {
      kv[tile][r] = *(const float4*)(kbase + (size_t)(tile * 32 + r) * DD);
      vv[tile][r] = *(const float4*)(vbase + (size_t)(tile * 32 + r) * DD);
    }

  // transpose-write in load order
#pragma unroll
  for (int tile = 0; tile < 4; ++tile)
#pragma unroll
    for (int c = 0; c < 4; ++c) {
      *(unsigned int*)&Kt[dq * 4 + c][tile * 32 + mr] =
          pk2(fc(kv[tile][0], c), fc(kv[tile][1], c));
      *(unsigned int*)&Vt[dq * 4 + c][tile * 32 + mr] =
          pk2(fc(vv[tile][0], c), fc(vv[tile][1], c));
    }
  __syncthreads();

  f32x4 acc[8];
#pragma unroll
  for (int b = 0; b < 8; ++b) acc[b] = (f32x4)(0.0f);

#pragma unroll
  for (int tile = 0; tile < 4; ++tile) {
    short8 a0 = *(const short8*)&Vt[wave * 16 + lr][tile * 32 + kg * 8];
#pragma unroll
    for (int tc = 0; tc < 8; ++tc) {
      short8 b = *(const short8*)&Kt[tc * 16 + lr][tile * 32 + kg * 8];
      acc[tc] = __builtin_amdgcn_mfma_f32_16x16x32_bf16(a0, b, acc[tc], 0, 0, 0);
    }
  }

  if (PARTIAL) {
    float* Pp = P + (size_t)blockIdx.x * (DD * DD);
#pragma unroll
    for (int tc = 0; tc < 8; ++tc)
#pragma unroll
      for (int r = 0; r < 4; ++r) {
        int i = wave * 16 + kg * 4 + r;
        int j = tc * 16 + lr;
        Pp[i * DD + j] = acc[tc][r];
      }
  } else {
    float* Wh = P + (size_t)bh * DD * DD;
#pragma unroll
    for (int tc = 0; tc < 8; ++tc)
#pragma unroll
      for (int r = 0; r < 4; ++r) {
        int i = wave * 16 + kg * 4 + r;
        int j = tc * 16 + lr;
        __hip_atomic_fetch_add(&Wh[i * DD + j], acc[tc][r],
                               __ATOMIC_RELAXED, __HIP_MEMORY_SCOPE_AGENT);
      }
  }
}

// ---------------------------------------------------------------------------
// Reduce: Wb[bh] (bf16, pre-scaled) = SCALE * sum_{c=0..15} P[bh*16+c].
// 131072 float4 tasks; grid 512 x 256, coalesced.
// ---------------------------------------------------------------------------
__global__ __launch_bounds__(256) void reduce_kernel(const float* __restrict__ P,
                                                     unsigned short* __restrict__ Wb) {
  const int task = blockIdx.x * 256 + threadIdx.x;  // bh*4096 + i4
  const int bh = task >> 12;
  const int i4 = task & 4095;
  const float4* p = (const float4*)P + (((size_t)bh << 4) << 12) + i4;
  float4 s = make_float4(0.f, 0.f, 0.f, 0.f);
#pragma unroll
  for (int c = 0; c < 16; ++c) {
    float4 x = p[(size_t)c << 12];
    s.x += x.x; s.y += x.y; s.z += x.z; s.w += x.w;
  }
  uint2 o;
  o.x = pk2(s.x * SCALE, s.y * SCALE);
  o.y = pk2(s.z * SCALE, s.w * SCALE);
  ((uint2*)Wb)[task] = o;
}

// fallback: fp32 W -> bf16 (pre-scaled)
__global__ __launch_bounds__(256) void cvt_kernel(const float* __restrict__ Wf,
                                                  unsigned short* __restrict__ Wb) {
#pragma unroll
  for (int j = 0; j < 4; ++j) {
    int o = blockIdx.x * 1024 + j * 256 + threadIdx.x;
    Wb[o] = f2bf(Wf[o] * SCALE);
  }
}

// ---------------------------------------------------------------------------
// Kernel 2: O[bh][l][d2] = sum_d1 Q[bh][l][d1] * Wb[bh][d2][d1]  (Wb pre-scaled)
// grid = 32 heads * 16 row-blocks (128 rows), block = 512 (8 waves x 16 rows).
// Q issued before W staging; q->bf16 converted while W staging lands.
// ---------------------------------------------------------------------------
__global__ __launch_bounds__(512, 4) void qw_kernel(const float* __restrict__ Qg,
                                                    const unsigned short* __restrict__ Wb,
                                                    float* __restrict__ Og) {
  const int bh = blockIdx.x >> 4;
  const int rblk = blockIdx.x & 15;
  const int t = threadIdx.x;
  const int wave = t >> 6;
  const int lane = t & 63;
  const int lr = lane & 15;
  const int kg = lane >> 4;

  __shared__ unsigned short Ws[128][136];  // [d2][d1] bf16, pad 8

  // 1) issue all Q loads (8 float4/thread; lane's 32B contiguous per ks)
  const float* Qb = Qg + ((size_t)bh * LL + rblk * 128 + wave * 16 + lr) * DD;
  float4 q[4][2];
#pragma unroll
  for (int ks = 0; ks < 4; ++ks)
#pragma unroll
    for (int j = 0; j < 2; ++j)
      q[ks][j] = *(const float4*)(Qb + ks * 32 + kg * 8 + j * 4);

  // 2) stage W (bf16, 32KB = 4 uint4/thread)
  const uint4* Wg = (const uint4*)(Wb + (size_t)bh * (DD * DD));
  uint4 wld[4];
#pragma unroll
  for (int it = 0; it < 4; ++it) wld[it] = Wg[t + it * 512];
#pragma unroll
  for (int it = 0; it < 4; ++it) {
    int g = t + it * 512;  // uint4 index; 16 per 128-short row
    int row = g >> 4;
    int c8 = (g & 15) * 8;
    *(uint4*)&Ws[row][c8] = wld[it];
  }

  // 3) convert q to bf16 fragments while W staging lands
  short8 abf[4];
#pragma unroll
  for (int ks = 0; ks < 4; ++ks)
#pragma unroll
    for (int j = 0; j < 2; ++j) {
      abf[ks][j * 4 + 0] = (short)f2bf(q[ks][j].x);
      abf[ks][j * 4 + 1] = (short)f2bf(q[ks][j].y);
      abf[ks][j * 4 + 2] = (short)f2bf(q[ks][j].z);
      abf[ks][j * 4 + 3] = (short)f2bf(q[ks][j].w);
    }
  __syncthreads();

  f32x4 acc[8];
#pragma unroll
  for (int b = 0; b < 8; ++b) acc[b] = (f32x4)(0.0f);

#pragma unroll
  for (int ks = 0; ks < 4; ++ks) {
#pragma unroll
    for (int tc = 0; tc < 8; ++tc) {
      short8 bfr = *(const short8*)&Ws[tc * 16 + lr][ks * 32 + kg * 8];
      acc[tc] = __builtin_amdgcn_mfma_f32_16x16x32_bf16(abf[ks], bfr, acc[tc], 0, 0, 0);
    }
  }

  float* Ob = Og + ((size_t)bh * LL + rblk * 128 + wave * 16) * DD;
#pragma unroll
  for (int tc = 0; tc < 8; ++tc)
#pragma unroll
    for (int r = 0; r < 4; ++r)
      Ob[(kg * 4 + r) * DD + tc * 16 + lr] = acc[tc][r];
}

extern "C" void kernel_launch(void* const* d_in, const int* in_sizes, int n_in,
                              void* d_out, int out_size, void* d_ws, size_t ws_size,
                              hipStream_t stream) {
  const float* Q = (const float*)d_in[0];
  const float* K = (const float*)d_in[1];
  const float* V = (const float*)d_in[2];
  float* O = (float*)d_out;

  const size_t P_BYTES = (size_t)512 * DD * DD * sizeof(float);             // 32 MB
  const size_t W_BYTES = (size_t)NH * DD * DD * sizeof(unsigned short);     // 1 MB

  if (ws_size >= P_BYTES + W_BYTES) {
    float* P = (float*)d_ws;
    unsigned short* Wb = (unsigned short*)((char*)d_ws + P_BYTES);
    ktv_kernel<true><<<dim3(512), dim3(512), 0, stream>>>(K, V, P);
    reduce_kernel<<<dim3(512), dim3(256), 0, stream>>>(P, Wb);
    qw_kernel<<<dim3(512), dim3(512), 0, stream>>>(Q, Wb, O);
  } else {
    // fallback: HW fp32 atomics into 2MB W, then convert+scale to bf16
    float* Wf = (float*)d_ws;
    unsigned short* Wb = (unsigned short*)((char*)d_ws + (size_t)NH * DD * DD * 4);
    hipMemsetAsync(d_ws, 0, (size_t)NH * DD * DD * sizeof(float), stream);
    ktv_kernel<false><<<dim3(512), dim3(512), 0, stream>>>(K, V, Wf);
    cvt_kernel<<<dim3(512), dim3(256), 0, stream>>>(Wf, Wb);
    qw_kernel<<<dim3(512), dim3(512), 0, stream>>>(Q, Wb, O);
  }
}